// Round 5
// baseline (566.232 us; speedup 1.0000x reference)
//
#include <hip/hip_runtime.h>

#define Lq 512
#define Bn 1024
#define Tq 48
#define NS 4     // batch streams per wave (ILP to hide LDS/HBM latency)
#define PF 8     // prefetch slots (supersteps of lead time)

typedef float f32x2 __attribute__((ext_vector_type(2)));
typedef float f32x4 __attribute__((ext_vector_type(4)));

// packed fp32 FMA (exact, proven round 3): acc += a*b elementwise
__device__ __forceinline__ f32x2 pk_fma(f32x2 a, f32x2 b, f32x2 acc) {
    asm("v_pk_fma_f32 %0, %1, %2, %0" : "+v"(acc) : "v"(a), "v"(b));
    return acc;
}

// ---------------- Forward algorithm (log partition function) ----------------
// 256 blocks x 64 threads; each wave advances NS=4 independent batch elements
// step-by-step. Lane j holds p_s[j] for each stream and shared W column j
// (fp32 pairs). Broadcast via LDS same-address reads; the 4 streams' FMA
// blocks fill each other's DS latency. Exact power-of-2 rescale every 4 steps.
__global__ __launch_bounds__(64) void crf_forward(
    const float* __restrict__ em, const int* __restrict__ mask,
    const float* __restrict__ startT, const float* __restrict__ endT,
    const float* __restrict__ trans, float* __restrict__ out)
{
    const int j  = threadIdx.x;            // 0..63
    const int b0 = blockIdx.x * NS;        // wave-uniform
    const int jc = j < Tq ? j : Tq - 1;
    const bool act = j < Tq;

    __shared__ float sh[NS * 64] __attribute__((aligned(16)));

    // shared W column j as fp32 pairs: w2[m] = (exp(T[2m][j]), exp(T[2m+1][j]))
    f32x2 w2[Tq / 2];
#pragma unroll
    for (int m = 0; m < Tq / 2; ++m) {
        float w0 = __expf(trans[(2 * m)     * Tq + jc]);
        float w1 = __expf(trans[(2 * m + 1) * Tq + jc]);
        w2[m] = act ? (f32x2){w0, w1} : (f32x2){0.0f, 0.0f};
    }

    float p[NS];
    int   c2[NS];
#pragma unroll
    for (int s = 0; s < NS; ++s) {
        p[s]  = act ? __expf(startT[jc] + em[((size_t)(b0 + s)) * Tq + jc]) : 0.0f;
        c2[s] = 0;
    }

    // prefetch buffers: slot d holds step (chunkbase + d)'s e and mask
    float eb[NS][PF];
    int   mb[NS][PF];
#pragma unroll
    for (int d = 0; d < PF; ++d)
#pragma unroll
        for (int s = 0; s < NS; ++s) {
            int t = 1 + d;
            eb[s][d] = em[((size_t)t * Bn + (b0 + s)) * Tq + jc];
            mb[s][d] = mask[t * Bn + (b0 + s)];
        }

    // one step for stream s: p_s = (sum_i p_s[i]*W[i][j]) * exp(e) if m else p_s
    auto step1 = [&](int s, float ev, int mv) {
        const f32x4* shp = (const f32x4*)&sh[s * 64];
        f32x2 a0 = {0.f, 0.f}, a1 = {0.f, 0.f}, a2 = {0.f, 0.f}, a3 = {0.f, 0.f};
#pragma unroll
        for (int q = 0; q < 12; q += 2) {
            f32x4 r0 = shp[q];
            f32x4 r1 = shp[q + 1];
            a0 = pk_fma(__builtin_shufflevector(r0, r0, 0, 1), w2[2 * q],     a0);
            a1 = pk_fma(__builtin_shufflevector(r0, r0, 2, 3), w2[2 * q + 1], a1);
            a2 = pk_fma(__builtin_shufflevector(r1, r1, 0, 1), w2[2 * q + 2], a2);
            a3 = pk_fma(__builtin_shufflevector(r1, r1, 2, 3), w2[2 * q + 3], a3);
        }
        f32x2 t0 = a0 + a1, t1 = a2 + a3, tt = t0 + t1;
        float sres = tt.x + tt.y;
        float pn = sres * __expf(ev);
        p[s] = mv ? pn : p[s];            // branch-free masked update
    };

    // superstep: advance all 4 streams one time-step using slot d
    auto superstep = [&](int d) {
#pragma unroll
        for (int s = 0; s < NS; ++s) sh[s * 64 + j] = p[s];   // DS in-order/wave
#pragma unroll
        for (int s = 0; s < NS; ++s) step1(s, eb[s][d], mb[s][d]);
    };

    // exact power-of-2 rescale from lane 0's exponent
    auto rescale = [&](int s) {
        int pb = __builtin_amdgcn_readlane(__float_as_int(p[s]), 0);
        int k  = (pb >> 23) - 126;
        p[s] *= __int_as_float((127 - k) << 23);   // * 2^-k, exact
        c2[s] += k;
    };

    // main: 63 chunks of 8 supersteps (steps 1..504); prefetch 8 ahead
    for (int c = 0; c < 63; ++c) {
        const int tbase = 1 + 8 * c;
#pragma unroll
        for (int d = 0; d < PF; ++d) {
            superstep(d);
            // refill slot d for next chunk (consumed 8 supersteps later)
            int tp  = tbase + d + PF;
            int tpc = tp <= Lq - 1 ? tp : Lq - 1;
#pragma unroll
            for (int s = 0; s < NS; ++s) {
                eb[s][d] = em[((size_t)tpc * Bn + (b0 + s)) * Tq + jc];
                mb[s][d] = tp <= Lq - 1 ? mask[tpc * Bn + (b0 + s)] : 0;
            }
            if (d == 3 || d == 7) {
#pragma unroll
                for (int s = 0; s < NS; ++s) rescale(s);
            }
        }
    }
    // epilogue: steps 505..511 from slots 0..6
#pragma unroll
    for (int d = 0; d < 7; ++d) {
        superstep(d);
        if (d == 3) {
#pragma unroll
            for (int s = 0; s < NS; ++s) rescale(s);
        }
    }

    // log_z per stream; lane 0 accumulates, one atomic per wave
    float ez = act ? __expf(endT[jc]) : 0.0f;
    float vsum = 0.0f;
#pragma unroll
    for (int s = 0; s < NS; ++s) {
        float z = p[s] * ez;
#pragma unroll
        for (int off = 32; off >= 1; off >>= 1)
            z += __shfl_xor(z, off, 64);
        double lz = (double)__logf(z) + (double)c2[s] * 0.6931471805599453;
        vsum += (float)(-lz);
    }
    if (j == 0) atomicAdd(out, vsum);
}

// ---------------- Numerator (gold-path score) ----------------
// Grid-stride over (t,b); block-reduce -> 1 atomic per block (512 total).
__global__ __launch_bounds__(256) void crf_llh(
    const float* __restrict__ em, const int* __restrict__ tags,
    const int* __restrict__ mask, const float* __restrict__ startT,
    const float* __restrict__ endT, const float* __restrict__ trans,
    float* __restrict__ out)
{
    float c = 0.0f;
    for (int id = blockIdx.x * blockDim.x + threadIdx.x; id < Lq * Bn;
         id += gridDim.x * blockDim.x) {
        int t  = id >> 10;          // / Bn (Bn = 1024)
        int bb = id & (Bn - 1);
        int tag = tags[id];
        int m_t = mask[id];
        if (t == 0) c += startT[tag];
        bool is_last;
        if (t < Lq - 1) {
            if (m_t) c += em[(size_t)id * Tq + tag];     // emis*mask[:-1]
            int tag1 = tags[id + Bn];
            int m1   = mask[id + Bn];
            if (m1) c += trans[tag * Tq + tag1];         // trans*mask[1:]
            is_last = (m_t != 0) && (m1 == 0);
        } else {
            is_last = (m_t != 0);
        }
        if (is_last) {
            c += endT[tag];
            int mL = mask[(Lq - 1) * Bn + bb];
            if (mL) c += em[((size_t)(Lq - 1) * Bn + bb) * Tq + tag];
        }
    }
#pragma unroll
    for (int off = 32; off >= 1; off >>= 1)
        c += __shfl_xor(c, off, 64);
    __shared__ float red[4];
    if ((threadIdx.x & 63) == 0) red[threadIdx.x >> 6] = c;
    __syncthreads();
    if (threadIdx.x == 0)
        atomicAdd(out, red[0] + red[1] + red[2] + red[3]);
}

extern "C" void kernel_launch(void* const* d_in, const int* in_sizes, int n_in,
                              void* d_out, int out_size, void* d_ws, size_t ws_size,
                              hipStream_t stream) {
    const float* em     = (const float*)d_in[0];
    const int*   tags   = (const int*)d_in[1];
    const int*   mask   = (const int*)d_in[2];
    const float* startT = (const float*)d_in[3];
    const float* endT   = (const float*)d_in[4];
    const float* trans  = (const float*)d_in[5];
    float* out = (float*)d_out;

    hipMemsetAsync(out, 0, sizeof(float), stream);
    crf_llh<<<512, 256, 0, stream>>>(em, tags, mask, startT, endT, trans, out);
    crf_forward<<<Bn / NS, 64, 0, stream>>>(em, mask, startT, endT, trans, out);
}

// Round 6
// 384.208 us; speedup vs baseline: 1.4738x; 1.4738x over previous
//
#include <hip/hip_runtime.h>

#define Lq 512
#define Bn 1024
#define Tq 48
#define NS 4     // batch streams per wave (ILP hides LDS/HBM latency)

typedef float f32x2 __attribute__((ext_vector_type(2)));
typedef float f32x4 __attribute__((ext_vector_type(4)));

// packed fp32 FMA (exact; validated rounds 3/5): acc += a*b elementwise
__device__ __forceinline__ f32x2 pk_fma(f32x2 a, f32x2 b, f32x2 acc) {
    asm("v_pk_fma_f32 %0, %1, %2, %0" : "+v"(acc) : "v"(a), "v"(b));
    return acc;
}
#define LO(v) __builtin_shufflevector((v), (v), 0, 1)
#define HI(v) __builtin_shufflevector((v), (v), 2, 3)

// one recursion step for one stream, everything in registers except the
// same-address LDS broadcast reads (conflict-free, DS pipe).
// P = (sum_i P[i]*W[i][j]) * exp(EV)  if MV else P
#define STEP1(P, SBUF, EV, MV) do {                                          \
    const f32x4* shp_ = (const f32x4*)&sh[(SBUF) * 64];                      \
    f32x4 r0_=shp_[0], r1_=shp_[1], r2_=shp_[2],  r3_=shp_[3];               \
    f32x4 r4_=shp_[4], r5_=shp_[5], r6_=shp_[6],  r7_=shp_[7];               \
    f32x4 r8_=shp_[8], r9_=shp_[9], r10_=shp_[10], r11_=shp_[11];            \
    f32x2 a0_={0.f,0.f}, a1_={0.f,0.f}, a2_={0.f,0.f}, a3_={0.f,0.f};        \
    a0_=pk_fma(LO(r0_),  w2[0],  a0_);  a1_=pk_fma(HI(r0_),  w2[1],  a1_);   \
    a2_=pk_fma(LO(r1_),  w2[2],  a2_);  a3_=pk_fma(HI(r1_),  w2[3],  a3_);   \
    a0_=pk_fma(LO(r2_),  w2[4],  a0_);  a1_=pk_fma(HI(r2_),  w2[5],  a1_);   \
    a2_=pk_fma(LO(r3_),  w2[6],  a2_);  a3_=pk_fma(HI(r3_),  w2[7],  a3_);   \
    a0_=pk_fma(LO(r4_),  w2[8],  a0_);  a1_=pk_fma(HI(r4_),  w2[9],  a1_);   \
    a2_=pk_fma(LO(r5_),  w2[10], a2_);  a3_=pk_fma(HI(r5_),  w2[11], a3_);   \
    a0_=pk_fma(LO(r6_),  w2[12], a0_);  a1_=pk_fma(HI(r6_),  w2[13], a1_);   \
    a2_=pk_fma(LO(r7_),  w2[14], a2_);  a3_=pk_fma(HI(r7_),  w2[15], a3_);   \
    a0_=pk_fma(LO(r8_),  w2[16], a0_);  a1_=pk_fma(HI(r8_),  w2[17], a1_);   \
    a2_=pk_fma(LO(r9_),  w2[18], a2_);  a3_=pk_fma(HI(r9_),  w2[19], a3_);   \
    a0_=pk_fma(LO(r10_), w2[20], a0_);  a1_=pk_fma(HI(r10_), w2[21], a1_);   \
    a2_=pk_fma(LO(r11_), w2[22], a2_);  a3_=pk_fma(HI(r11_), w2[23], a3_);   \
    f32x2 t01_ = a0_ + a1_, t23_ = a2_ + a3_, tt_ = t01_ + t23_;             \
    float s_ = tt_.x + tt_.y;                                                \
    float pn_ = s_ * __expf(EV);                                             \
    (P) = (MV) ? pn_ : (P);                                                  \
} while (0)

// advance all 4 streams one time-step using prefetch slot D
#define SUPER(D) do {                                                        \
    sh[j] = p0; sh[64 + j] = p1; sh[128 + j] = p2; sh[192 + j] = p3;         \
    STEP1(p0, 0, e0_##D, m0_##D);                                            \
    STEP1(p1, 1, e1_##D, m1_##D);                                            \
    STEP1(p2, 2, e2_##D, m2_##D);                                            \
    STEP1(p3, 3, e3_##D, m3_##D);                                            \
} while (0)

// refill slot D with time-step T's raw e (exp at consume!) and mask
#define LOAD_SLOT(D, T) do {                                                 \
    int t_ = (T); int v_ = (t_ <= Lq - 1); int tc_ = v_ ? t_ : (Lq - 1);     \
    unsigned eo_ = (unsigned)tc_ * (Bn * Tq) + boff;                         \
    e0_##D = em[eo_];          e1_##D = em[eo_ + Tq];                        \
    e2_##D = em[eo_ + 2*Tq];   e3_##D = em[eo_ + 3*Tq];                      \
    unsigned mo_ = (unsigned)tc_ * Bn + (unsigned)b0;                        \
    m0_##D = v_ ? mask[mo_]     : 0;  m1_##D = v_ ? mask[mo_ + 1] : 0;       \
    m2_##D = v_ ? mask[mo_ + 2] : 0;  m3_##D = v_ ? mask[mo_ + 3] : 0;       \
} while (0)

// exact power-of-2 rescale from lane 0's exponent
#define RESCALE(P, C2) do {                                                  \
    int pb_ = __builtin_amdgcn_readlane(__float_as_int(P), 0);               \
    int k_ = (pb_ >> 23) - 126;                                              \
    (P) *= __int_as_float((127 - k_) << 23);                                 \
    (C2) += k_;                                                              \
} while (0)
#define RESCALE4 do { RESCALE(p0, c20); RESCALE(p1, c21);                    \
                      RESCALE(p2, c22); RESCALE(p3, c23); } while (0)

// ---------------- Forward algorithm (log partition function) ----------------
// 256 blocks x 1 wave; each wave advances 4 independent batch elements.
// All prefetch state in NAMED scalars (round-5 scratch-spill fix).
__global__ __launch_bounds__(64, 1) void crf_forward(
    const float* __restrict__ em, const int* __restrict__ mask,
    const float* __restrict__ startT, const float* __restrict__ endT,
    const float* __restrict__ trans, float* __restrict__ out)
{
    const int j  = threadIdx.x;            // 0..63
    const int b0 = blockIdx.x * NS;        // wave-uniform
    const int jc = j < Tq ? j : Tq - 1;
    const bool act = j < Tq;
    const unsigned boff = (unsigned)b0 * Tq + (unsigned)jc;

    __shared__ float sh[NS * 64] __attribute__((aligned(16)));

    // shared W column j as fp32 pairs: w2[m] = (exp(T[2m][j]), exp(T[2m+1][j]))
    f32x2 w2[Tq / 2];
#pragma unroll
    for (int m = 0; m < Tq / 2; ++m) {
        float w0 = __expf(trans[(2 * m)     * Tq + jc]);
        float w1 = __expf(trans[(2 * m + 1) * Tq + jc]);
        w2[m] = act ? (f32x2){w0, w1} : (f32x2){0.0f, 0.0f};
    }

    float p0, p1, p2, p3;
    int c20 = 0, c21 = 0, c22 = 0, c23 = 0;
    p0 = act ? __expf(startT[jc] + em[(size_t)(b0 + 0) * Tq + jc]) : 0.0f;
    p1 = act ? __expf(startT[jc] + em[(size_t)(b0 + 1) * Tq + jc]) : 0.0f;
    p2 = act ? __expf(startT[jc] + em[(size_t)(b0 + 2) * Tq + jc]) : 0.0f;
    p3 = act ? __expf(startT[jc] + em[(size_t)(b0 + 3) * Tq + jc]) : 0.0f;

    // 8 prefetch slots x 4 streams, all named scalars
    float e0_0,e0_1,e0_2,e0_3,e0_4,e0_5,e0_6,e0_7;
    float e1_0,e1_1,e1_2,e1_3,e1_4,e1_5,e1_6,e1_7;
    float e2_0,e2_1,e2_2,e2_3,e2_4,e2_5,e2_6,e2_7;
    float e3_0,e3_1,e3_2,e3_3,e3_4,e3_5,e3_6,e3_7;
    int   m0_0,m0_1,m0_2,m0_3,m0_4,m0_5,m0_6,m0_7;
    int   m1_0,m1_1,m1_2,m1_3,m1_4,m1_5,m1_6,m1_7;
    int   m2_0,m2_1,m2_2,m2_3,m2_4,m2_5,m2_6,m2_7;
    int   m3_0,m3_1,m3_2,m3_3,m3_4,m3_5,m3_6,m3_7;

    LOAD_SLOT(0, 1); LOAD_SLOT(1, 2); LOAD_SLOT(2, 3); LOAD_SLOT(3, 4);
    LOAD_SLOT(4, 5); LOAD_SLOT(5, 6); LOAD_SLOT(6, 7); LOAD_SLOT(7, 8);

    // 64 chunks x 8 supersteps cover t = 1..512 (t=512 is a masked no-op)
    for (int c = 0; c < 64; ++c) {
        const int tb = 1 + 8 * c;
        SUPER(0); LOAD_SLOT(0, tb + 8);
        SUPER(1); LOAD_SLOT(1, tb + 9);
        SUPER(2); LOAD_SLOT(2, tb + 10);
        SUPER(3); LOAD_SLOT(3, tb + 11); RESCALE4;
        SUPER(4); LOAD_SLOT(4, tb + 12);
        SUPER(5); LOAD_SLOT(5, tb + 13);
        SUPER(6); LOAD_SLOT(6, tb + 14);
        SUPER(7); LOAD_SLOT(7, tb + 15); RESCALE4;
    }

    // log_z per stream; lane 0 accumulates, one atomic per wave
    float ez = act ? __expf(endT[jc]) : 0.0f;
    float z0 = p0 * ez, z1 = p1 * ez, z2 = p2 * ez, z3 = p3 * ez;
#pragma unroll
    for (int off = 32; off >= 1; off >>= 1) {
        z0 += __shfl_xor(z0, off, 64);
        z1 += __shfl_xor(z1, off, 64);
        z2 += __shfl_xor(z2, off, 64);
        z3 += __shfl_xor(z3, off, 64);
    }
    if (j == 0) {
        const double LN2 = 0.6931471805599453;
        double v = (double)__logf(z0) + (double)c20 * LN2
                 + (double)__logf(z1) + (double)c21 * LN2
                 + (double)__logf(z2) + (double)c22 * LN2
                 + (double)__logf(z3) + (double)c23 * LN2;
        atomicAdd(out, (float)(-v));
    }
}

// ---------------- Numerator (gold-path score) ----------------
// Grid-stride over (t,b); block-reduce -> 1 atomic per block (512 total).
__global__ __launch_bounds__(256) void crf_llh(
    const float* __restrict__ em, const int* __restrict__ tags,
    const int* __restrict__ mask, const float* __restrict__ startT,
    const float* __restrict__ endT, const float* __restrict__ trans,
    float* __restrict__ out)
{
    float c = 0.0f;
    for (int id = blockIdx.x * blockDim.x + threadIdx.x; id < Lq * Bn;
         id += gridDim.x * blockDim.x) {
        int t  = id >> 10;          // / Bn (Bn = 1024)
        int bb = id & (Bn - 1);
        int tag = tags[id];
        int m_t = mask[id];
        if (t == 0) c += startT[tag];
        bool is_last;
        if (t < Lq - 1) {
            if (m_t) c += em[(size_t)id * Tq + tag];     // emis*mask[:-1]
            int tag1 = tags[id + Bn];
            int m1   = mask[id + Bn];
            if (m1) c += trans[tag * Tq + tag1];         // trans*mask[1:]
            is_last = (m_t != 0) && (m1 == 0);
        } else {
            is_last = (m_t != 0);
        }
        if (is_last) {
            c += endT[tag];
            int mL = mask[(Lq - 1) * Bn + bb];
            if (mL) c += em[((size_t)(Lq - 1) * Bn + bb) * Tq + tag];
        }
    }
#pragma unroll
    for (int off = 32; off >= 1; off >>= 1)
        c += __shfl_xor(c, off, 64);
    __shared__ float red[4];
    if ((threadIdx.x & 63) == 0) red[threadIdx.x >> 6] = c;
    __syncthreads();
    if (threadIdx.x == 0)
        atomicAdd(out, red[0] + red[1] + red[2] + red[3]);
}

extern "C" void kernel_launch(void* const* d_in, const int* in_sizes, int n_in,
                              void* d_out, int out_size, void* d_ws, size_t ws_size,
                              hipStream_t stream) {
    const float* em     = (const float*)d_in[0];
    const int*   tags   = (const int*)d_in[1];
    const int*   mask   = (const int*)d_in[2];
    const float* startT = (const float*)d_in[3];
    const float* endT   = (const float*)d_in[4];
    const float* trans  = (const float*)d_in[5];
    float* out = (float*)d_out;

    hipMemsetAsync(out, 0, sizeof(float), stream);
    crf_llh<<<512, 256, 0, stream>>>(em, tags, mask, startT, endT, trans, out);
    crf_forward<<<Bn / NS, 64, 0, stream>>>(em, mask, startT, endT, trans, out);
}

// Round 7
// 174.849 us; speedup vs baseline: 3.2384x; 2.1974x over previous
//
#include <hip/hip_runtime.h>

#define Lq 512
#define Bn 1024
#define Tq 48

#define IF(x) __int_as_float(x)

// 48 readlanes, bursted (all independent, no consumer in between), then
// 48 v_fmac_f32 each reading one fresh SGPR directly (legal: 1 SGPR/VALU op).
// P = (sum_i P[i]*W[i][j]) * EXV  if MV else P
#define STEPA(EXV, MV) do {                                                   \
    int pu_ = __float_as_int(p);                                              \
    const int s0_=__builtin_amdgcn_readlane(pu_,0),  s1_=__builtin_amdgcn_readlane(pu_,1),   \
              s2_=__builtin_amdgcn_readlane(pu_,2),  s3_=__builtin_amdgcn_readlane(pu_,3),   \
              s4_=__builtin_amdgcn_readlane(pu_,4),  s5_=__builtin_amdgcn_readlane(pu_,5),   \
              s6_=__builtin_amdgcn_readlane(pu_,6),  s7_=__builtin_amdgcn_readlane(pu_,7),   \
              s8_=__builtin_amdgcn_readlane(pu_,8),  s9_=__builtin_amdgcn_readlane(pu_,9),   \
              s10_=__builtin_amdgcn_readlane(pu_,10),s11_=__builtin_amdgcn_readlane(pu_,11), \
              s12_=__builtin_amdgcn_readlane(pu_,12),s13_=__builtin_amdgcn_readlane(pu_,13), \
              s14_=__builtin_amdgcn_readlane(pu_,14),s15_=__builtin_amdgcn_readlane(pu_,15), \
              s16_=__builtin_amdgcn_readlane(pu_,16),s17_=__builtin_amdgcn_readlane(pu_,17), \
              s18_=__builtin_amdgcn_readlane(pu_,18),s19_=__builtin_amdgcn_readlane(pu_,19), \
              s20_=__builtin_amdgcn_readlane(pu_,20),s21_=__builtin_amdgcn_readlane(pu_,21), \
              s22_=__builtin_amdgcn_readlane(pu_,22),s23_=__builtin_amdgcn_readlane(pu_,23), \
              s24_=__builtin_amdgcn_readlane(pu_,24),s25_=__builtin_amdgcn_readlane(pu_,25), \
              s26_=__builtin_amdgcn_readlane(pu_,26),s27_=__builtin_amdgcn_readlane(pu_,27), \
              s28_=__builtin_amdgcn_readlane(pu_,28),s29_=__builtin_amdgcn_readlane(pu_,29), \
              s30_=__builtin_amdgcn_readlane(pu_,30),s31_=__builtin_amdgcn_readlane(pu_,31), \
              s32_=__builtin_amdgcn_readlane(pu_,32),s33_=__builtin_amdgcn_readlane(pu_,33), \
              s34_=__builtin_amdgcn_readlane(pu_,34),s35_=__builtin_amdgcn_readlane(pu_,35), \
              s36_=__builtin_amdgcn_readlane(pu_,36),s37_=__builtin_amdgcn_readlane(pu_,37), \
              s38_=__builtin_amdgcn_readlane(pu_,38),s39_=__builtin_amdgcn_readlane(pu_,39), \
              s40_=__builtin_amdgcn_readlane(pu_,40),s41_=__builtin_amdgcn_readlane(pu_,41), \
              s42_=__builtin_amdgcn_readlane(pu_,42),s43_=__builtin_amdgcn_readlane(pu_,43), \
              s44_=__builtin_amdgcn_readlane(pu_,44),s45_=__builtin_amdgcn_readlane(pu_,45), \
              s46_=__builtin_amdgcn_readlane(pu_,46),s47_=__builtin_amdgcn_readlane(pu_,47); \
    float a0_ = 0.f, a1_ = 0.f, a2_ = 0.f, a3_ = 0.f;                         \
    a0_=fmaf(IF(s0_), w[0], a0_);  a1_=fmaf(IF(s1_), w[1], a1_);              \
    a2_=fmaf(IF(s2_), w[2], a2_);  a3_=fmaf(IF(s3_), w[3], a3_);              \
    a0_=fmaf(IF(s4_), w[4], a0_);  a1_=fmaf(IF(s5_), w[5], a1_);              \
    a2_=fmaf(IF(s6_), w[6], a2_);  a3_=fmaf(IF(s7_), w[7], a3_);              \
    a0_=fmaf(IF(s8_), w[8], a0_);  a1_=fmaf(IF(s9_), w[9], a1_);              \
    a2_=fmaf(IF(s10_),w[10],a2_);  a3_=fmaf(IF(s11_),w[11],a3_);              \
    a0_=fmaf(IF(s12_),w[12],a0_);  a1_=fmaf(IF(s13_),w[13],a1_);              \
    a2_=fmaf(IF(s14_),w[14],a2_);  a3_=fmaf(IF(s15_),w[15],a3_);              \
    a0_=fmaf(IF(s16_),w[16],a0_);  a1_=fmaf(IF(s17_),w[17],a1_);              \
    a2_=fmaf(IF(s18_),w[18],a2_);  a3_=fmaf(IF(s19_),w[19],a3_);              \
    a0_=fmaf(IF(s20_),w[20],a0_);  a1_=fmaf(IF(s21_),w[21],a1_);              \
    a2_=fmaf(IF(s22_),w[22],a2_);  a3_=fmaf(IF(s23_),w[23],a3_);              \
    a0_=fmaf(IF(s24_),w[24],a0_);  a1_=fmaf(IF(s25_),w[25],a1_);              \
    a2_=fmaf(IF(s26_),w[26],a2_);  a3_=fmaf(IF(s27_),w[27],a3_);              \
    a0_=fmaf(IF(s28_),w[28],a0_);  a1_=fmaf(IF(s29_),w[29],a1_);              \
    a2_=fmaf(IF(s30_),w[30],a2_);  a3_=fmaf(IF(s31_),w[31],a3_);              \
    a0_=fmaf(IF(s32_),w[32],a0_);  a1_=fmaf(IF(s33_),w[33],a1_);              \
    a2_=fmaf(IF(s34_),w[34],a2_);  a3_=fmaf(IF(s35_),w[35],a3_);              \
    a0_=fmaf(IF(s36_),w[36],a0_);  a1_=fmaf(IF(s37_),w[37],a1_);              \
    a2_=fmaf(IF(s38_),w[38],a2_);  a3_=fmaf(IF(s39_),w[39],a3_);              \
    a0_=fmaf(IF(s40_),w[40],a0_);  a1_=fmaf(IF(s41_),w[41],a1_);              \
    a2_=fmaf(IF(s42_),w[42],a2_);  a3_=fmaf(IF(s43_),w[43],a3_);              \
    a0_=fmaf(IF(s44_),w[44],a0_);  a1_=fmaf(IF(s45_),w[45],a1_);              \
    a2_=fmaf(IF(s46_),w[46],a2_);  a3_=fmaf(IF(s47_),w[47],a3_);              \
    float ssum_ = (a0_ + a1_) + (a2_ + a3_);                                  \
    float pn_ = ssum_ * (EXV);                                                \
    p = (MV) ? pn_ : p;                                                       \
} while (0)

// refill slot D with step T: raw e -> exp NOW (8 steps before use, off chain)
#define LOAD_SLOT(D, T) do {                                                  \
    int t_ = (T); int v_ = (t_ <= Lq - 1); int tc_ = v_ ? t_ : (Lq - 1);      \
    ex_##D = __expf(em[(size_t)tc_ * (Bn * Tq) + boff]);                      \
    m_##D  = v_ ? mask[tc_ * Bn + b] : 0;                                     \
} while (0)

// exact power-of-2 rescale from lane 0's exponent bits
#define RESCALE do {                                                          \
    int pb_ = __builtin_amdgcn_readlane(__float_as_int(p), 0);                \
    int k_ = (pb_ >> 23) - 126;                                               \
    p *= __int_as_float((127 - k_) << 23);                                    \
    c2 += k_;                                                                 \
} while (0)

// ---------------- Forward algorithm (log partition function) ----------------
// 1024 blocks x 64 threads = 1 wave/SIMD chip-wide (max TLP for this op).
// Broadcast via BURSTED v_readlane (48 up front, no SALU repacking, no LDS),
// consumed directly as SGPR operands of v_fmac_f32.
__global__ __launch_bounds__(64, 1) void crf_forward(
    const float* __restrict__ em, const int* __restrict__ mask,
    const float* __restrict__ startT, const float* __restrict__ endT,
    const float* __restrict__ trans, float* __restrict__ out)
{
    const int j  = threadIdx.x;          // 0..63
    const int b  = blockIdx.x;           // wave-uniform
    const int jc = j < Tq ? j : Tq - 1;
    const bool act = j < Tq;
    const unsigned boff = (unsigned)b * Tq + (unsigned)jc;

    // W column j in 48 VGPRs (constant-indexed, fully unrolled)
    float w[Tq];
#pragma unroll
    for (int i = 0; i < Tq; ++i) {
        float wv = __expf(trans[i * Tq + jc]);
        w[i] = act ? wv : 0.0f;
    }

    float p = act ? __expf(startT[jc] + em[boff]) : 0.0f;
    int c2 = 0;

    // 8 prefetch slots, named scalars (round-5/6 spill lesson)
    float ex_0, ex_1, ex_2, ex_3, ex_4, ex_5, ex_6, ex_7;
    int   m_0, m_1, m_2, m_3, m_4, m_5, m_6, m_7;
    LOAD_SLOT(0, 1); LOAD_SLOT(1, 2); LOAD_SLOT(2, 3); LOAD_SLOT(3, 4);
    LOAD_SLOT(4, 5); LOAD_SLOT(5, 6); LOAD_SLOT(6, 7); LOAD_SLOT(7, 8);

    // 64 chunks x 8 steps cover t = 1..512 (t=512 is a masked no-op)
    for (int c = 0; c < 64; ++c) {
        const int tb = 1 + 8 * c;
        STEPA(ex_0, m_0); LOAD_SLOT(0, tb + 8);
        STEPA(ex_1, m_1); LOAD_SLOT(1, tb + 9);
        STEPA(ex_2, m_2); LOAD_SLOT(2, tb + 10);
        STEPA(ex_3, m_3); LOAD_SLOT(3, tb + 11); RESCALE;
        STEPA(ex_4, m_4); LOAD_SLOT(4, tb + 12);
        STEPA(ex_5, m_5); LOAD_SLOT(5, tb + 13);
        STEPA(ex_6, m_6); LOAD_SLOT(6, tb + 14);
        STEPA(ex_7, m_7); LOAD_SLOT(7, tb + 15); RESCALE;
    }

    // log_z = ln(sum_j P[j]*exp(end[j])) + c2*ln2 ; accumulate -log_z
    float ez = act ? __expf(endT[jc]) : 0.0f;
    float z = p * ez;
#pragma unroll
    for (int off = 32; off >= 1; off >>= 1)
        z += __shfl_xor(z, off, 64);
    if (j == 0) {
        double lz = (double)__logf(z) + (double)c2 * 0.6931471805599453;
        atomicAdd(out, (float)(-lz));
    }
}

// ---------------- Numerator (gold-path score) ----------------
// Grid-stride over (t,b); block-reduce -> 1 atomic per block (512 total).
__global__ __launch_bounds__(256) void crf_llh(
    const float* __restrict__ em, const int* __restrict__ tags,
    const int* __restrict__ mask, const float* __restrict__ startT,
    const float* __restrict__ endT, const float* __restrict__ trans,
    float* __restrict__ out)
{
    float c = 0.0f;
    for (int id = blockIdx.x * blockDim.x + threadIdx.x; id < Lq * Bn;
         id += gridDim.x * blockDim.x) {
        int t  = id >> 10;          // / Bn (Bn = 1024)
        int bb = id & (Bn - 1);
        int tag = tags[id];
        int m_t = mask[id];
        if (t == 0) c += startT[tag];
        bool is_last;
        if (t < Lq - 1) {
            if (m_t) c += em[(size_t)id * Tq + tag];     // emis*mask[:-1]
            int tag1 = tags[id + Bn];
            int m1   = mask[id + Bn];
            if (m1) c += trans[tag * Tq + tag1];         // trans*mask[1:]
            is_last = (m_t != 0) && (m1 == 0);
        } else {
            is_last = (m_t != 0);
        }
        if (is_last) {
            c += endT[tag];
            int mL = mask[(Lq - 1) * Bn + bb];
            if (mL) c += em[((size_t)(Lq - 1) * Bn + bb) * Tq + tag];
        }
    }
#pragma unroll
    for (int off = 32; off >= 1; off >>= 1)
        c += __shfl_xor(c, off, 64);
    __shared__ float red[4];
    if ((threadIdx.x & 63) == 0) red[threadIdx.x >> 6] = c;
    __syncthreads();
    if (threadIdx.x == 0)
        atomicAdd(out, red[0] + red[1] + red[2] + red[3]);
}

extern "C" void kernel_launch(void* const* d_in, const int* in_sizes, int n_in,
                              void* d_out, int out_size, void* d_ws, size_t ws_size,
                              hipStream_t stream) {
    const float* em     = (const float*)d_in[0];
    const int*   tags   = (const int*)d_in[1];
    const int*   mask   = (const int*)d_in[2];
    const float* startT = (const float*)d_in[3];
    const float* endT   = (const float*)d_in[4];
    const float* trans  = (const float*)d_in[5];
    float* out = (float*)d_out;

    hipMemsetAsync(out, 0, sizeof(float), stream);
    crf_llh<<<512, 256, 0, stream>>>(em, tags, mask, startT, endT, trans, out);
    crf_forward<<<Bn, 64, 0, stream>>>(em, mask, startT, endT, trans, out);
}